// Round 10
// baseline (157.228 us; speedup 1.0000x reference)
//
#include <hip/hip_runtime.h>

#define N     384
#define BSZ   192
#define NM1   383
#define D     1024
#define DELTA 0.1f
#define NT    24                    // 16-row panels / tiles per dim
#define NTILES (NT * (NT + 1) / 2)  // 300 upper-tri tiles
#define PANEL 16384                 // halfs per panel: 16 rows * 1024

typedef __attribute__((ext_vector_type(8))) short bf16x8;
typedef __attribute__((ext_vector_type(4))) float f32x4;

__device__ __forceinline__ const float* feat_row(const float* feats, int i) {
    // features laid out [192][2][1024]; logical row i of the [384,1024] concat
    int b = (i < BSZ) ? i : (i - BSZ);
    int s = (i < BSZ) ? 0 : 1;
    return feats + (size_t)(b * 2 + s) * D;
}

__device__ __forceinline__ unsigned short f2bf(float x) {  // RNE f32->bf16
    unsigned u = __builtin_bit_cast(unsigned, x);
    u = (u + 0x7FFFu + ((u >> 16) & 1u)) >> 16;
    return (unsigned short)u;
}
__device__ __forceinline__ float bf2f(unsigned short h) {
    unsigned u = ((unsigned)h) << 16;
    return __builtin_bit_cast(float, u);
}

// ---- PROBE: ~60us wall-clock spins (s_memrealtime = 100 MHz XTAL). No
// output; only purpose is to appear in top-5 and timestamp-bracket k_gram.
__global__ void k_spinA() {
    unsigned long long t0 = __builtin_amdgcn_s_memrealtime();
    while (__builtin_amdgcn_s_memrealtime() - t0 < 6000ULL)
        __builtin_amdgcn_s_sleep(2);
}
__global__ void k_spinB() {
    unsigned long long t0 = __builtin_amdgcn_s_memrealtime();
    while (__builtin_amdgcn_s_memrealtime() - t0 < 6000ULL)
        __builtin_amdgcn_s_sleep(2);
}

// Fragment-major tiled index: (row, k) -> [row/16][k/8][row%16][k%8]
__device__ __forceinline__ size_t tidx(int row, int k) {
    return (size_t)(row >> 4) * PANEL + (size_t)(k >> 3) * 128
         + (size_t)(row & 15) * 8 + (k & 7);
}

// f32 -> (H, L) bf16 split in fragment-major layout + |f|^2; 4 rows/block.
__global__ __launch_bounds__(256) void k_cvt(const float* __restrict__ feats,
                                             unsigned short* __restrict__ Ht,
                                             unsigned short* __restrict__ Lt,
                                             float* __restrict__ sq,
                                             unsigned* __restrict__ counter) {
    const int lane = threadIdx.x & 63, wv = threadIdx.x >> 6;
    const int i = blockIdx.x * 4 + wv;
    if (blockIdx.x == 0 && threadIdx.x == 0) *counter = 0u;
    const float4* f4 = (const float4*)feat_row(feats, i);
    float p = 0.f;
#pragma unroll
    for (int c = 0; c < 4; ++c) {
        float4 v = f4[lane + 64 * c];
        p = fmaf(v.x, v.x, p); p = fmaf(v.y, v.y, p);
        p = fmaf(v.z, v.z, p); p = fmaf(v.w, v.w, p);
        ushort4 h, l;
        h.x = f2bf(v.x); l.x = f2bf(v.x - bf2f(h.x));
        h.y = f2bf(v.y); l.y = f2bf(v.y - bf2f(h.y));
        h.z = f2bf(v.z); l.z = f2bf(v.z - bf2f(h.z));
        h.w = f2bf(v.w); l.w = f2bf(v.w - bf2f(h.w));
        const int e = 4 * (lane + 64 * c);
        const size_t o = tidx(i, e);       // e%8 in {0,4}: 8B-aligned slot
        *(ushort4*)(Ht + o) = h;
        *(ushort4*)(Lt + o) = l;
    }
#pragma unroll
    for (int off = 32; off; off >>= 1) p += __shfl_xor(p, off);
    if (lane == 0) sq[i] = p;
}

// Gram via MFMA on fragment-major H/L (unchanged from R9).
__global__ __launch_bounds__(256) void k_gram(const unsigned short* __restrict__ Ht,
                                              const unsigned short* __restrict__ Lt,
                                              const float* __restrict__ sq,
                                              float* __restrict__ z) {
    int t = blockIdx.x, bi = 0;
    while (t >= NT - bi) { t -= NT - bi; ++bi; }
    const int bj = bi + t;
    const bool diag = (bi == bj);

    const int tid = threadIdx.x;
    const int lane = tid & 63, wv = tid >> 6;

    const size_t aBase = (size_t)bi * PANEL + (size_t)(wv * 32 + (lane >> 4)) * 128
                       + (size_t)(lane & 15) * 8;
    const size_t bBase = (size_t)bj * PANEL + (size_t)(wv * 32 + (lane >> 4)) * 128
                       + (size_t)(lane & 15) * 8;

    f32x4 aHH = {0.f,0.f,0.f,0.f}, aHL = {0.f,0.f,0.f,0.f}, aLH = {0.f,0.f,0.f,0.f};
#pragma unroll
    for (int s = 0; s < 8; ++s) {
        bf16x8 aH = *(const bf16x8*)(Ht + aBase + s * 512);
        bf16x8 aL = *(const bf16x8*)(Lt + aBase + s * 512);
        bf16x8 bH = *(const bf16x8*)(Ht + bBase + s * 512);
        bf16x8 bL = *(const bf16x8*)(Lt + bBase + s * 512);
        aHH = __builtin_amdgcn_mfma_f32_16x16x32_bf16(aH, bH, aHH, 0, 0, 0);
        aHL = __builtin_amdgcn_mfma_f32_16x16x32_bf16(aH, bL, aHL, 0, 0, 0);
        aLH = __builtin_amdgcn_mfma_f32_16x16x32_bf16(aL, bH, aLH, 0, 0, 0);
    }
    __shared__ f32x4 red[4][64];
    red[wv][lane] = aHH + aHL + aLH;
    __syncthreads();
    const int ls = tid & 63, r = tid >> 6;
    float g = red[0][ls][r] + red[1][ls][r] + red[2][ls][r] + red[3][ls][r];
    // C/D layout (verified): col = lane&15, row = (lane>>4)*4 + reg
    const int jj = bj * 16 + (ls & 15);
    const int ii = bi * 16 + ((ls >> 4) << 2) + r;
    if (ii != jj && (!diag || ii < jj)) {
        float sd = fmaxf(sq[ii] + sq[jj] - 2.f * g, 0.f);
        float v  = sqrtf(sd);
        z[ii * NM1 + (jj < ii ? jj : jj - 1)] = v;
        z[jj * NM1 + (ii < jj ? ii : ii - 1)] = v;
    }
}

// One block per row, 512 threads (unchanged from R9).
__global__ __launch_bounds__(512) void k_main(const float* __restrict__ z,
                                              const int* __restrict__ labels,
                                              float* __restrict__ partial,
                                              unsigned* __restrict__ counter,
                                              float* __restrict__ out) {
    const int i = blockIdx.x, tid = threadIdx.x;
    __shared__ float zbuf[NM1];
    __shared__ unsigned char yrow[NM1];
    __shared__ int cnt[64], startv[64], cur[64];
    __shared__ float rankd[64];
    __shared__ float2 zr[N];      // sorted (z, rank*DELTA); slot 383 = pad
    __shared__ unsigned grs[N];   // lo | hi<<9 per sorted slot
    __shared__ int lastFlag;

    if (tid < 64) cnt[tid] = 0;
    for (int k = tid; k < NM1; k += 512) zbuf[k] = z[i * NM1 + k];
    __syncthreads();
    const int li = labels[(i < BSZ) ? i : (i - BSZ)];
    for (int k = tid; k < NM1; k += 512) {
        int col = k + (k >= i ? 1 : 0);
        int ya  = abs(li - labels[(col < BSZ) ? col : (col - BSZ)]);
        yrow[k] = (unsigned char)ya;
        atomicAdd(&cnt[ya], 1);
    }
    __syncthreads();
    if (tid == 0) {
        int c = 0, r = 0;
        for (int v = 0; v < 64; ++v) {
            startv[v] = c;
            rankd[v]  = (float)r * DELTA;
            if (cnt[v] > 0) ++r;
            c += cnt[v];
        }
    }
    __syncthreads();
    if (tid < 64) cur[tid] = startv[tid];
    __syncthreads();
    for (int k = tid; k < NM1; k += 512) {
        int ya  = yrow[k];
        int pos = atomicAdd(&cur[ya], 1);
        zr[pos]  = make_float2(zbuf[k], rankd[ya]);
        grs[pos] = (unsigned)startv[ya] | ((unsigned)(startv[ya] + cnt[ya]) << 9);
    }
    if (tid == 0) zr[NM1] = make_float2(0.f, 0.f);
    __syncthreads();

    // all-pairs term: (|zk-zj| - |rk-rj|)^2, one k-slot per thread
    const bool  kv  = (tid < NM1);
    const int   k0  = kv ? tid : NM1;      // pad slot for inactive threads
    const float zk0 = zr[k0].x, rk0 = zr[k0].y;

    float s0 = 0.f;
#define PAIRQ(q) do { \
        float t0 = fabsf(zk0 - (q).x) - fabsf(rk0 - (q).y); s0 = fmaf(t0, t0, s0); \
    } while (0)
    int j = 0;
    for (; j + 8 <= NM1; j += 8) {
        float2 q0 = zr[j],   q1 = zr[j+1], q2 = zr[j+2], q3 = zr[j+3];
        float2 q4 = zr[j+4], q5 = zr[j+5], q6 = zr[j+6], q7 = zr[j+7];
        PAIRQ(q0); PAIRQ(q1); PAIRQ(q2); PAIRQ(q3);
        PAIRQ(q4); PAIRQ(q5); PAIRQ(q6); PAIRQ(q7);
    }
    for (; j < NM1; ++j) { float2 q = zr[j]; PAIRQ(q); }
#undef PAIRQ
    if (!kv) s0 = 0.f;

    // correction over same-y pairs: a*sigmoid(a-DELTA) - a^2 over [lo,hi)
    float cs = 0.f;
    if (kv) {
        const float    zj = zr[tid].x;
        const unsigned g  = grs[tid];
        const int lo = g & 0x1FF;
        const int hi = (g >> 9) & 0x1FF;
        for (int k = lo; k < hi; ++k) {
            float a = fabsf(zr[k].x - zj);
            cs += a * __builtin_amdgcn_rcpf(1.f + __expf(DELTA - a)) - a * a;
        }
    }

    float sum = s0 + cs;
#pragma unroll
    for (int off = 32; off; off >>= 1) sum += __shfl_xor(sum, off);
    __shared__ float part[8];
    if ((tid & 63) == 0) part[tid >> 6] = sum;
    __syncthreads();
    if (tid == 0) {
        float ps = 0.f;
#pragma unroll
        for (int w = 0; w < 8; ++w) ps += part[w];
        partial[i] = ps;
        __threadfence();
        unsigned old = atomicAdd(counter, 1u);
        lastFlag = (old == N - 1);
    }
    __syncthreads();

    if (lastFlag) {
        // atomic reads bypass any stale per-XCD L2 lines
        double s = 0.0;
        for (int t2 = tid; t2 < N; t2 += 512) s += (double)atomicAdd(&partial[t2], 0.f);
#pragma unroll
        for (int off = 32; off; off >>= 1) s += __shfl_xor(s, off);
        __shared__ double dp[8];
        if ((tid & 63) == 0) dp[tid >> 6] = s;
        __syncthreads();
        if (tid == 0) {
            double ds = 0.0;
#pragma unroll
            for (int w = 0; w < 8; ++w) ds += dp[w];
            const double M = (double)N * (double)NM1 * (double)NM1;
            out[0] = (float)(ds / M);
        }
    }
}

extern "C" void kernel_launch(void* const* d_in, const int* in_sizes, int n_in,
                              void* d_out, int out_size, void* d_ws, size_t ws_size,
                              hipStream_t stream) {
    const float* feats  = (const float*)d_in[0];
    const int*   labels = (const int*)d_in[1];
    float*       out    = (float*)d_out;

    // ws layout (~2.2 MB total):
    char* ws = (char*)d_ws;
    float*          sq      = (float*)ws;                          // 1536 B
    unsigned*       counter = (unsigned*)(ws + 2048);              // 4 B
    float*          partial = (float*)(ws + 4096);                 // 1536 B
    unsigned short* Ht      = (unsigned short*)(ws + 16384);       // 768 KiB
    unsigned short* Lt      = (unsigned short*)(ws + 16384 + 786432);        // 768 KiB
    float*          z       = (float*)(ws + 16384 + 2 * 786432);   // 588 KiB

    // PROBE ORDER: spans in the profile timestamps decompose the budget:
    //   spinA.End -> spinB.Start = k_gram + 2 boundaries
    k_cvt  <<<N / 4, 256, 0, stream>>>(feats, Ht, Lt, sq, counter);
    k_spinA<<<1, 64, 0, stream>>>();
    k_gram <<<NTILES, 256, 0, stream>>>(Ht, Lt, sq, z);
    k_spinB<<<1, 64, 0, stream>>>();
    k_main <<<N, 512, 0, stream>>>(z, labels, partial, counter, out);
}

// Round 11
// 37.383 us; speedup vs baseline: 4.2059x; 4.2059x over previous
//
#include <hip/hip_runtime.h>

#define N     384
#define BSZ   192
#define NM1   383
#define D     1024
#define DELTA 0.1f
#define NT    24                    // 16-row panels / tiles per dim
#define NTILES (NT * (NT + 1) / 2)  // 300 upper-tri tiles
#define PANEL 16384                 // halfs per panel: 16 rows * 1024

typedef __attribute__((ext_vector_type(8))) short bf16x8;
typedef __attribute__((ext_vector_type(4))) float f32x4;

__device__ __forceinline__ const float* feat_row(const float* feats, int i) {
    // features laid out [192][2][1024]; logical row i of the [384,1024] concat
    int b = (i < BSZ) ? i : (i - BSZ);
    int s = (i < BSZ) ? 0 : 1;
    return feats + (size_t)(b * 2 + s) * D;
}

__device__ __forceinline__ unsigned short f2bf(float x) {  // RNE f32->bf16
    unsigned u = __builtin_bit_cast(unsigned, x);
    u = (u + 0x7FFFu + ((u >> 16) & 1u)) >> 16;
    return (unsigned short)u;
}
__device__ __forceinline__ float bf2f(unsigned short h) {
    unsigned u = ((unsigned)h) << 16;
    return __builtin_bit_cast(float, u);
}

// Fragment-major tiled index: (row, k) -> [row/16][k/8][row%16][k%8]
__device__ __forceinline__ size_t tidx(int row, int k) {
    return (size_t)(row >> 4) * PANEL + (size_t)(k >> 3) * 128
         + (size_t)(row & 15) * 8 + (k & 7);
}

// f32 -> (H, L) bf16 split in fragment-major layout + |f|^2; 4 rows/block.
__global__ __launch_bounds__(256) void k_cvt(const float* __restrict__ feats,
                                             unsigned short* __restrict__ Ht,
                                             unsigned short* __restrict__ Lt,
                                             float* __restrict__ sq,
                                             unsigned* __restrict__ counter) {
    const int lane = threadIdx.x & 63, wv = threadIdx.x >> 6;
    const int i = blockIdx.x * 4 + wv;
    if (blockIdx.x == 0 && threadIdx.x == 0) *counter = 0u;
    const float4* f4 = (const float4*)feat_row(feats, i);
    float p = 0.f;
#pragma unroll
    for (int c = 0; c < 4; ++c) {
        float4 v = f4[lane + 64 * c];
        p = fmaf(v.x, v.x, p); p = fmaf(v.y, v.y, p);
        p = fmaf(v.z, v.z, p); p = fmaf(v.w, v.w, p);
        ushort4 h, l;
        h.x = f2bf(v.x); l.x = f2bf(v.x - bf2f(h.x));
        h.y = f2bf(v.y); l.y = f2bf(v.y - bf2f(h.y));
        h.z = f2bf(v.z); l.z = f2bf(v.z - bf2f(h.z));
        h.w = f2bf(v.w); l.w = f2bf(v.w - bf2f(h.w));
        const int e = 4 * (lane + 64 * c);
        const size_t o = tidx(i, e);       // e%8 in {0,4}: 8B-aligned slot
        *(ushort4*)(Ht + o) = h;
        *(ushort4*)(Lt + o) = l;
    }
#pragma unroll
    for (int off = 32; off; off >>= 1) p += __shfl_xor(p, off);
    if (lane == 0) sq[i] = p;
}

// Gram via MFMA on fragment-major H/L (byte-identical to R9).
__global__ __launch_bounds__(256) void k_gram(const unsigned short* __restrict__ Ht,
                                              const unsigned short* __restrict__ Lt,
                                              const float* __restrict__ sq,
                                              float* __restrict__ z) {
    int t = blockIdx.x, bi = 0;
    while (t >= NT - bi) { t -= NT - bi; ++bi; }
    const int bj = bi + t;
    const bool diag = (bi == bj);

    const int tid = threadIdx.x;
    const int lane = tid & 63, wv = tid >> 6;

    const size_t aBase = (size_t)bi * PANEL + (size_t)(wv * 32 + (lane >> 4)) * 128
                       + (size_t)(lane & 15) * 8;
    const size_t bBase = (size_t)bj * PANEL + (size_t)(wv * 32 + (lane >> 4)) * 128
                       + (size_t)(lane & 15) * 8;

    f32x4 aHH = {0.f,0.f,0.f,0.f}, aHL = {0.f,0.f,0.f,0.f}, aLH = {0.f,0.f,0.f,0.f};
#pragma unroll
    for (int s = 0; s < 8; ++s) {
        bf16x8 aH = *(const bf16x8*)(Ht + aBase + s * 512);
        bf16x8 aL = *(const bf16x8*)(Lt + aBase + s * 512);
        bf16x8 bH = *(const bf16x8*)(Ht + bBase + s * 512);
        bf16x8 bL = *(const bf16x8*)(Lt + bBase + s * 512);
        aHH = __builtin_amdgcn_mfma_f32_16x16x32_bf16(aH, bH, aHH, 0, 0, 0);
        aHL = __builtin_amdgcn_mfma_f32_16x16x32_bf16(aH, bL, aHL, 0, 0, 0);
        aLH = __builtin_amdgcn_mfma_f32_16x16x32_bf16(aL, bH, aLH, 0, 0, 0);
    }
    __shared__ f32x4 red[4][64];
    red[wv][lane] = aHH + aHL + aLH;
    __syncthreads();
    const int ls = tid & 63, r = tid >> 6;
    float g = red[0][ls][r] + red[1][ls][r] + red[2][ls][r] + red[3][ls][r];
    // C/D layout (verified): col = lane&15, row = (lane>>4)*4 + reg
    const int jj = bj * 16 + (ls & 15);
    const int ii = bi * 16 + ((ls >> 4) << 2) + r;
    if (ii != jj && (!diag || ii < jj)) {
        float sd = fmaxf(sq[ii] + sq[jj] - 2.f * g, 0.f);
        float v  = sqrtf(sd);
        z[ii * NM1 + (jj < ii ? jj : jj - 1)] = v;
        z[jj * NM1 + (ii < jj ? ii : ii - 1)] = v;
    }
}

// One block per row, 512 threads (byte-identical to R9).
__global__ __launch_bounds__(512) void k_main(const float* __restrict__ z,
                                              const int* __restrict__ labels,
                                              float* __restrict__ partial,
                                              unsigned* __restrict__ counter,
                                              float* __restrict__ out) {
    const int i = blockIdx.x, tid = threadIdx.x;
    __shared__ float zbuf[NM1];
    __shared__ unsigned char yrow[NM1];
    __shared__ int cnt[64], startv[64], cur[64];
    __shared__ float rankd[64];
    __shared__ float2 zr[N];      // sorted (z, rank*DELTA); slot 383 = pad
    __shared__ unsigned grs[N];   // lo | hi<<9 per sorted slot
    __shared__ int lastFlag;

    if (tid < 64) cnt[tid] = 0;
    for (int k = tid; k < NM1; k += 512) zbuf[k] = z[i * NM1 + k];
    __syncthreads();
    const int li = labels[(i < BSZ) ? i : (i - BSZ)];
    for (int k = tid; k < NM1; k += 512) {
        int col = k + (k >= i ? 1 : 0);
        int ya  = abs(li - labels[(col < BSZ) ? col : (col - BSZ)]);
        yrow[k] = (unsigned char)ya;
        atomicAdd(&cnt[ya], 1);
    }
    __syncthreads();
    if (tid == 0) {
        int c = 0, r = 0;
        for (int v = 0; v < 64; ++v) {
            startv[v] = c;
            rankd[v]  = (float)r * DELTA;
            if (cnt[v] > 0) ++r;
            c += cnt[v];
        }
    }
    __syncthreads();
    if (tid < 64) cur[tid] = startv[tid];
    __syncthreads();
    for (int k = tid; k < NM1; k += 512) {
        int ya  = yrow[k];
        int pos = atomicAdd(&cur[ya], 1);
        zr[pos]  = make_float2(zbuf[k], rankd[ya]);
        grs[pos] = (unsigned)startv[ya] | ((unsigned)(startv[ya] + cnt[ya]) << 9);
    }
    if (tid == 0) zr[NM1] = make_float2(0.f, 0.f);
    __syncthreads();

    // all-pairs term: (|zk-zj| - |rk-rj|)^2, one k-slot per thread
    const bool  kv  = (tid < NM1);
    const int   k0  = kv ? tid : NM1;      // pad slot for inactive threads
    const float zk0 = zr[k0].x, rk0 = zr[k0].y;

    float s0 = 0.f;
#define PAIRQ(q) do { \
        float t0 = fabsf(zk0 - (q).x) - fabsf(rk0 - (q).y); s0 = fmaf(t0, t0, s0); \
    } while (0)
    int j = 0;
    for (; j + 8 <= NM1; j += 8) {
        float2 q0 = zr[j],   q1 = zr[j+1], q2 = zr[j+2], q3 = zr[j+3];
        float2 q4 = zr[j+4], q5 = zr[j+5], q6 = zr[j+6], q7 = zr[j+7];
        PAIRQ(q0); PAIRQ(q1); PAIRQ(q2); PAIRQ(q3);
        PAIRQ(q4); PAIRQ(q5); PAIRQ(q6); PAIRQ(q7);
    }
    for (; j < NM1; ++j) { float2 q = zr[j]; PAIRQ(q); }
#undef PAIRQ
    if (!kv) s0 = 0.f;

    // correction over same-y pairs: a*sigmoid(a-DELTA) - a^2 over [lo,hi)
    float cs = 0.f;
    if (kv) {
        const float    zj = zr[tid].x;
        const unsigned g  = grs[tid];
        const int lo = g & 0x1FF;
        const int hi = (g >> 9) & 0x1FF;
        for (int k = lo; k < hi; ++k) {
            float a = fabsf(zr[k].x - zj);
            cs += a * __builtin_amdgcn_rcpf(1.f + __expf(DELTA - a)) - a * a;
        }
    }

    float sum = s0 + cs;
#pragma unroll
    for (int off = 32; off; off >>= 1) sum += __shfl_xor(sum, off);
    __shared__ float part[8];
    if ((tid & 63) == 0) part[tid >> 6] = sum;
    __syncthreads();
    if (tid == 0) {
        float ps = 0.f;
#pragma unroll
        for (int w = 0; w < 8; ++w) ps += part[w];
        partial[i] = ps;
        __threadfence();
        unsigned old = atomicAdd(counter, 1u);
        lastFlag = (old == N - 1);
    }
    __syncthreads();

    if (lastFlag) {
        // atomic reads bypass any stale per-XCD L2 lines
        double s = 0.0;
        for (int t2 = tid; t2 < N; t2 += 512) s += (double)atomicAdd(&partial[t2], 0.f);
#pragma unroll
        for (int off = 32; off; off >>= 1) s += __shfl_xor(s, off);
        __shared__ double dp[8];
        if ((tid & 63) == 0) dp[tid >> 6] = s;
        __syncthreads();
        if (tid == 0) {
            double ds = 0.0;
#pragma unroll
            for (int w = 0; w < 8; ++w) ds += dp[w];
            const double M = (double)N * (double)NM1 * (double)NM1;
            out[0] = (float)(ds / M);
        }
    }
}

extern "C" void kernel_launch(void* const* d_in, const int* in_sizes, int n_in,
                              void* d_out, int out_size, void* d_ws, size_t ws_size,
                              hipStream_t stream) {
    const float* feats  = (const float*)d_in[0];
    const int*   labels = (const int*)d_in[1];
    float*       out    = (float*)d_out;

    // ws layout (~2.2 MB total):
    char* ws = (char*)d_ws;
    float*          sq      = (float*)ws;                          // 1536 B
    unsigned*       counter = (unsigned*)(ws + 2048);              // 4 B
    float*          partial = (float*)(ws + 4096);                 // 1536 B
    unsigned short* Ht      = (unsigned short*)(ws + 16384);       // 768 KiB
    unsigned short* Lt      = (unsigned short*)(ws + 16384 + 786432);        // 768 KiB
    float*          z       = (float*)(ws + 16384 + 2 * 786432);   // 588 KiB

    // DIFFERENTIAL PROBE: k_gram launched twice (idempotent — rewrites the
    // same z). gram_time = T11 - T9 - ~1us boundary. Reverted next round.
    k_cvt <<<N / 4, 256, 0, stream>>>(feats, Ht, Lt, sq, counter);
    k_gram<<<NTILES, 256, 0, stream>>>(Ht, Lt, sq, z);
    k_gram<<<NTILES, 256, 0, stream>>>(Ht, Lt, sq, z);
    k_main<<<N, 512, 0, stream>>>(z, labels, partial, counter, out);
}